// Round 9
// baseline (87.501 us; speedup 1.0000x reference)
//
#include <hip/hip_runtime.h>
#include <math.h>

#define T_COLS 147456   // N_R*3*N_D*C = 1024*3*16*3
#define BS 8
#define NU 49152        // T_COLS/3: u = (part*1024 + r)*16 + d

// ws layout (float offsets)
#define OFF_ME      0                              // 256*8
#define OFF_THETA   2048                           // 8*3*49152 (permuted theta_t)
#define OFF_MULP    (OFF_THETA + BS*T_COLS)        // 8*3*1024*16
#define OFF_ADDSUM  (OFF_MULP + 8*3*1024*16)       // 8*3*1024
#define OFF_Q       (OFF_ADDSUM + 8*3*1024)        // 8*3*1024

// fast tanh: 1 - 2/(exp(2x)+1); abs err ~2e-7, inf-safe
__device__ __forceinline__ float tanh_fast(float x) {
    float e = __expf(2.f * x);
    return 1.f - 2.f * __builtin_amdgcn_rcpf(e + 1.f);
}

// K1: me[k][b] = mean over 64 spatial of patch_emb[b,:,:,k]
__global__ __launch_bounds__(1024) void k1_mean(const float* __restrict__ pe,
                                                float* __restrict__ me) {
    int b = blockIdx.x;                     // 8
    int k = threadIdx.x & 255, qd = threadIdx.x >> 8;
    const float* p = pe + (size_t)b * 16384 + qd * 4096 + k;
    float s = 0.f;
#pragma unroll
    for (int i = 0; i < 16; i++) s += p[i * 256];
    __shared__ float part[4][256];
    part[qd][k] = s;
    __syncthreads();
    if (threadIdx.x < 256) {
        float v = part[0][k] + part[1][k] + part[2][k] + part[3][k];
        me[k * 8 + b] = v * (1.f / 64.f);
    }
}

// K2: theta_t[(b*3+c)*49152 + u] = sum_k me[b][k]*w[k][t] + bt[t], t = 3u+c.
// 768 blocks x 192 threads = exactly 3 blocks/CU. (R6 version, unchanged.)
// NOTE: launched TWICE this round as a timing instrument — idempotent.
__global__ __launch_bounds__(192) void k2_gemm(const float* __restrict__ w,
                                               const float* __restrict__ bt,
                                               const float* __restrict__ me,
                                               float* __restrict__ tt) {
    __shared__ __align__(16) float lme[2048];   // [k][b]
    __shared__ float lt[8][192];
    int tid = threadIdx.x;
    for (int i = tid; i < 2048; i += 192) lme[i] = me[i];
    __syncthreads();

    int t = blockIdx.x * 192 + tid;
    const float* wp = w + t;
    float bv = bt[t];

    float acc[8];
#pragma unroll
    for (int b = 0; b < 8; b++) acc[b] = 0.f;

#pragma unroll 32
    for (int k = 0; k < 256; k++) {
        float wv = wp[(size_t)k * T_COLS];
        const float4* m4 = reinterpret_cast<const float4*>(&lme[k * 8]);
        float4 m0 = m4[0], m1 = m4[1];
        acc[0] += m0.x * wv;
        acc[1] += m0.y * wv;
        acc[2] += m0.z * wv;
        acc[3] += m0.w * wv;
        acc[4] += m1.x * wv;
        acc[5] += m1.y * wv;
        acc[6] += m1.z * wv;
        acc[7] += m1.w * wv;
    }
#pragma unroll
    for (int b = 0; b < 8; b++) lt[b][tid] = acc[b] + bv;
    __syncthreads();

    // permuted write: wave c handles channel c; 64 lanes = 64 consecutive u
    int u0 = blockIdx.x * 64;
    int j = tid & 63;
    int c = tid >> 6;                    // 0..2 (wave-uniform)
#pragma unroll
    for (int b = 0; b < 8; b++) {
        float v = lt[b][j * 3 + c];
        tt[(size_t)(b * 3 + c) * NU + u0 + j] = v;
    }
}

// kC: fused softmax + tanh*sm + A/s reduction + p-iteration + q.
// One block per (b,c), 1024 threads (1 range row each). All theta reads coalesced.
#define MVL_STRIDE 1028
__global__ __launch_bounds__(1024) void kC(const float* __restrict__ tt,
                                           float* __restrict__ mulp,
                                           float* __restrict__ addsum,
                                           float* __restrict__ q) {
    int bc = blockIdx.x;                 // 24
    int r = threadIdx.x;                 // 0..1023
    int lane = r & 63, wv = r >> 6;      // 16 waves
    const float4* base = reinterpret_cast<const float4*>(tt + (size_t)bc * NU);

    __shared__ float redm[16 * 16];          // [wave][d]
    __shared__ float gm[16], ginv[16];
    __shared__ float mvl[16 * MVL_STRIDE];   // transposed mv, padded
    __shared__ float sred[1024];
    __shared__ float Ash[256];
    __shared__ float svl[16], pl[16];

    // ---- 1) mix load (part 2, float4-coalesced) + block max per d ----
    float mx[16];
    {
        float4 x0 = base[8192 + r * 4 + 0];
        float4 x1 = base[8192 + r * 4 + 1];
        float4 x2 = base[8192 + r * 4 + 2];
        float4 x3 = base[8192 + r * 4 + 3];
        mx[0] = x0.x; mx[1] = x0.y; mx[2] = x0.z; mx[3] = x0.w;
        mx[4] = x1.x; mx[5] = x1.y; mx[6] = x1.z; mx[7] = x1.w;
        mx[8] = x2.x; mx[9] = x2.y; mx[10] = x2.z; mx[11] = x2.w;
        mx[12] = x3.x; mx[13] = x3.y; mx[14] = x3.z; mx[15] = x3.w;
    }
    {
        float wred[16];
#pragma unroll
        for (int d = 0; d < 16; d++) wred[d] = mx[d];
#pragma unroll
        for (int m = 32; m > 0; m >>= 1)
#pragma unroll
            for (int d = 0; d < 16; d++)
                wred[d] = fmaxf(wred[d], __shfl_xor(wred[d], m));
        if (lane == 0) {
#pragma unroll
            for (int d = 0; d < 16; d++) redm[wv * 16 + d] = wred[d];
        }
    }
    __syncthreads();
    if (r < 16) {
        float m = -1e30f;
#pragma unroll
        for (int w = 0; w < 16; w++) m = fmaxf(m, redm[w * 16 + r]);
        gm[r] = m;
    }
    __syncthreads();

    // ---- 2) exp + block sum per d ----
    {
        float wred[16];
#pragma unroll
        for (int d = 0; d < 16; d++) {
            mx[d] = __expf(mx[d] - gm[d]);
            wred[d] = mx[d];
        }
#pragma unroll
        for (int m = 32; m > 0; m >>= 1)
#pragma unroll
            for (int d = 0; d < 16; d++)
                wred[d] += __shfl_xor(wred[d], m);
        if (lane == 0) {
#pragma unroll
            for (int d = 0; d < 16; d++) redm[wv * 16 + d] = wred[d];
        }
    }
    __syncthreads();
    if (r < 16) {
        float s = 0.f;
#pragma unroll
        for (int w = 0; w < 16; w++) s += redm[w * 16 + r];
        ginv[r] = 1.f / s;
    }
    __syncthreads();
#pragma unroll
    for (int d = 0; d < 16; d++) mx[d] *= ginv[d];   // mx = softmax sm[r][d]

    // ---- 3) add phase (part 1) ----
    float asum = 0.f;
    {
        float4 a0 = base[4096 + r * 4 + 0];
        float4 a1 = base[4096 + r * 4 + 1];
        float4 a2 = base[4096 + r * 4 + 2];
        float4 a3 = base[4096 + r * 4 + 3];
        float av[16];
        av[0] = a0.x; av[1] = a0.y; av[2] = a0.z; av[3] = a0.w;
        av[4] = a1.x; av[5] = a1.y; av[6] = a1.z; av[7] = a1.w;
        av[8] = a2.x; av[9] = a2.y; av[10] = a2.z; av[11] = a2.w;
        av[12] = a3.x; av[13] = a3.y; av[14] = a3.z; av[15] = a3.w;
#pragma unroll
        for (int d = 0; d < 16; d++) asum += tanh_fast(av[d]) * mx[d];
    }
    addsum[(size_t)bc * 1024 + r] = asum;
    sred[r] = asum;

    // ---- 4) mul phase (part 0) ----
    float mv[16];
    {
        float4 m0 = base[r * 4 + 0];
        float4 m1 = base[r * 4 + 1];
        float4 m2 = base[r * 4 + 2];
        float4 m3 = base[r * 4 + 3];
        mv[0] = m0.x; mv[1] = m0.y; mv[2] = m0.z; mv[3] = m0.w;
        mv[4] = m1.x; mv[5] = m1.y; mv[6] = m1.z; mv[7] = m1.w;
        mv[8] = m2.x; mv[9] = m2.y; mv[10] = m2.z; mv[11] = m2.w;
        mv[12] = m3.x; mv[13] = m3.y; mv[14] = m3.z; mv[15] = m3.w;
#pragma unroll
        for (int d = 0; d < 16; d++) mv[d] = tanh_fast(mv[d]) * mx[d];
    }
    {
        float4* mp = reinterpret_cast<float4*>(&mulp[((size_t)bc * 1024 + r) * 16]);
        mp[0] = make_float4(mv[0], mv[1], mv[2], mv[3]);
        mp[1] = make_float4(mv[4], mv[5], mv[6], mv[7]);
        mp[2] = make_float4(mv[8], mv[9], mv[10], mv[11]);
        mp[3] = make_float4(mv[12], mv[13], mv[14], mv[15]);
    }
#pragma unroll
    for (int d = 0; d < 16; d++) mvl[d * MVL_STRIDE + r] = mv[d];
    __syncthreads();

    // ---- 5) A[dd][d], sv[dd] ----
    if (r < 256) {
        int dd = r >> 4, d = r & 15;
        int di = dd >> 2, dj = dd & 3;
        const float* bse = &mvl[d * MVL_STRIDE + di * 256 + dj * 8];
        float s = 0.f;
        for (int a = 0; a < 8; a++) {
#pragma unroll
            for (int e = 0; e < 8; e++) s += bse[a * 32 + e];
        }
        Ash[r] = s * (1.f / 64.f);
    }
    if (r < 16) {
        int di = r >> 2, dj = r & 3;
        float s = 0.f;
        for (int a = 0; a < 8; a++)
#pragma unroll
            for (int e = 0; e < 8; e++) s += sred[di * 256 + a * 32 + dj * 8 + e];
        svl[r] = s * (1.f / 64.f);
    }
    __syncthreads();

    // ---- 6) p_8 iteration on wave 0, 16-lane shfl broadcast ----
    if (r < 64) {
        int d2 = r & 15;
        float arow[16];
#pragma unroll
        for (int d = 0; d < 16; d++) arow[d] = Ash[d2 * 16 + d];
        float sv = svl[d2];
        float pd = 0.f;
        for (int it = 0; it < 8; it++) {
            float x = sv;
#pragma unroll
            for (int d = 0; d < 16; d++) x += arow[d] * __shfl(pd, d, 16);
            pd = x;
        }
        if (r < 16) pl[r] = pd;
    }
    __syncthreads();

    // ---- 7) q[r] ----
    {
        float x = asum;
#pragma unroll
        for (int d = 0; d < 16; d++) x += mv[d] * pl[d];
        q[(size_t)bc * 1024 + r] = x;
    }
}

// K5: final image. Block = (b, ri): 8 rows x 256 cols x 3 c. q staged in LDS.
__global__ __launch_bounds__(512) void k5_final(const float* __restrict__ mulp,
                                                const float* __restrict__ addsum,
                                                const float* __restrict__ q,
                                                float* __restrict__ out) {
    int blk = blockIdx.x;                 // 256
    int b = blk >> 5, ri = blk & 31;
    int tid = threadIdx.x;                // 512
    __shared__ float ql[3072];            // q for 3 channels of this b
    for (int i = tid; i < 3072; i += 512) ql[i] = q[(size_t)b * 3072 + i];
    __syncthreads();

    int h = tid >> 6;                     // 0..7 (wave-uniform)
    int rj = (tid >> 1) & 31;             // 0..31
    int wh = tid & 1;                     // w-half
    int r = ri * 32 + rj;

    float mr[3][16];
    float as[3];
#pragma unroll
    for (int c = 0; c < 3; c++) {
        const float4* mp4 = reinterpret_cast<const float4*>(
            &mulp[((size_t)(b * 3 + c) * 1024 + r) * 16]);
        float4 v0 = mp4[0], v1 = mp4[1], v2 = mp4[2], v3 = mp4[3];
        mr[c][0] = v0.x; mr[c][1] = v0.y; mr[c][2] = v0.z; mr[c][3] = v0.w;
        mr[c][4] = v1.x; mr[c][5] = v1.y; mr[c][6] = v1.z; mr[c][7] = v1.w;
        mr[c][8] = v2.x; mr[c][9] = v2.y; mr[c][10] = v2.z; mr[c][11] = v2.w;
        mr[c][12] = v3.x; mr[c][13] = v3.y; mr[c][14] = v3.z; mr[c][15] = v3.w;
        as[c] = addsum[(size_t)(b * 3 + c) * 1024 + r];
    }

    float acc[3][4];
#pragma unroll
    for (int c = 0; c < 3; c++)
#pragma unroll
        for (int w = 0; w < 4; w++) acc[c][w] = as[c];

#pragma unroll
    for (int di = 0; di < 4; di++) {
        int qrow = (di * 8 + h) * 32;
#pragma unroll
        for (int dj = 0; dj < 4; dj++) {
#pragma unroll
            for (int c = 0; c < 3; c++) {
                float m = mr[c][di * 4 + dj];
                const float* qb = &ql[c * 1024 + qrow + dj * 8 + wh * 4];
                acc[c][0] += m * qb[0];
                acc[c][1] += m * qb[1];
                acc[c][2] += m * qb[2];
                acc[c][3] += m * qb[3];
            }
        }
    }

    int i = ri * 8 + h;
    int j0 = rj * 8 + wh * 4;
    float4* ob = reinterpret_cast<float4*>(
        &out[((size_t)(b * 256 + i) * 256 + j0) * 3]);
    ob[0] = make_float4(acc[0][0], acc[1][0], acc[2][0], acc[0][1]);
    ob[1] = make_float4(acc[1][1], acc[2][1], acc[0][2], acc[1][2]);
    ob[2] = make_float4(acc[2][2], acc[0][3], acc[1][3], acc[2][3]);
}

extern "C" void kernel_launch(void* const* d_in, const int* in_sizes, int n_in,
                              void* d_out, int out_size, void* d_ws, size_t ws_size,
                              hipStream_t stream) {
    const float* pe = (const float*)d_in[0];   // (8,8,8,256)
    const float* w  = (const float*)d_in[1];   // (256,147456)
    const float* bt = (const float*)d_in[2];   // (147456,)
    float* ws = (float*)d_ws;

    float* me     = ws + OFF_ME;
    float* tt     = ws + OFF_THETA;
    float* mulp   = ws + OFF_MULP;
    float* addsum = ws + OFF_ADDSUM;
    float* q      = ws + OFF_Q;
    float* out = (float*)d_out;

    k1_mean<<<8, 1024, 0, stream>>>(pe, me);
    k2_gemm<<<T_COLS / 192, 192, 0, stream>>>(w, bt, me, tt);   // 768 blocks
    k2_gemm<<<T_COLS / 192, 192, 0, stream>>>(w, bt, me, tt);   // TIMING PROBE: idempotent 2nd launch; dur delta vs R6 == k2 time
    kC<<<24, 1024, 0, stream>>>(tt, mulp, addsum, q);
    k5_final<<<256, 512, 0, stream>>>(mulp, addsum, q, out);
}

// Round 10
// 60.762 us; speedup vs baseline: 1.4401x; 1.4401x over previous
//
#include <hip/hip_runtime.h>
#include <math.h>

#define T_COLS 147456   // N_R*3*N_D*C = 1024*3*16*3
#define NU 49152        // T_COLS/3: u = (part*1024 + r)*16 + d

// ws layout (float offsets)
#define OFF_ME      0                              // 256*8
#define OFF_THETA   2048                           // 8*3*49152 (permuted theta_t)
#define OFF_MULP    (OFF_THETA + 8*T_COLS)         // 8*3*1024*16
#define OFF_ADDSUM  (OFF_MULP + 8*3*1024*16)       // 8*3*1024
#define OFF_Q       (OFF_ADDSUM + 8*3*1024)        // 8*3*1024
#define OFF_BAR     (OFF_Q + 8*3*1024)             // 2 uint barrier counters

// fast tanh: 1 - 2/(exp(2x)+1); abs err ~2e-7, inf-safe
__device__ __forceinline__ float tanh_fast(float x) {
    float e = __expf(2.f * x);
    return 1.f - 2.f * __builtin_amdgcn_rcpf(e + 1.f);
}

// Manual grid barrier: requires ALL gridDim.x blocks co-resident.
__device__ __forceinline__ void gridbar(unsigned int* bar, unsigned int target) {
    __syncthreads();
    if (threadIdx.x == 0) {
        __threadfence();                       // release: make my writes visible
        atomicAdd(bar, 1u);
        while (atomicAdd(bar, 0u) < target) __builtin_amdgcn_s_sleep(2);
        __threadfence();                       // acquire
    }
    __syncthreads();
}

// k1z: zero barrier counters (ws not re-poisoned between replays!) + me[k][b]
__global__ __launch_bounds__(1024) void k1z(const float* __restrict__ pe,
                                            float* __restrict__ me,
                                            unsigned int* __restrict__ bar) {
    if (blockIdx.x == 0 && threadIdx.x < 2) bar[threadIdx.x] = 0u;
    int b = blockIdx.x;                     // 8
    int k = threadIdx.x & 255, qd = threadIdx.x >> 8;
    const float* p = pe + (size_t)b * 16384 + qd * 4096 + k;
    float s = 0.f;
#pragma unroll
    for (int i = 0; i < 16; i++) s += p[i * 256];
    __shared__ float part[4][256];
    part[qd][k] = s;
    __syncthreads();
    if (threadIdx.x < 256) {
        float v = part[0][k] + part[1][k] + part[2][k] + part[3][k];
        me[k * 8 + b] = v * (1.f / 64.f);
    }
}

// mega: P2 GEMV+tt | bar | P3 softmax/tanh/A/p/q | bar | P4 final image.
// 768 blocks x 256 threads, 3 blocks/CU co-resident by construction:
// LDS 44.4 KB -> 3/CU; __launch_bounds__(256,3) caps VGPR at 170.
__global__ __launch_bounds__(256, 3) void mega(
        const float* __restrict__ w, const float* __restrict__ bt,
        const float* __restrict__ me, float* __restrict__ tt,
        float* __restrict__ mulp, float* __restrict__ addsum,
        float* __restrict__ q, float* __restrict__ out,
        unsigned int* __restrict__ bar) {
    const int bid = blockIdx.x;    // 768
    const int tid = threadIdx.x;   // 256

    __shared__ __align__(16) float lme[2048];      // P2 (8 KB)
    __shared__ float lt[8][192];                   // P2 (6 KB)
    __shared__ __align__(16) float red[256 * 16];  // P3 (16 KB)
    __shared__ float sred[256];                    // P3 (1 KB)
    __shared__ float Ash[256];                     // P3 (1 KB)
    __shared__ float gmax[16], ginv[16], svl[16], pl[16];
    __shared__ float ql3[3072];                    // P4 (12 KB)

    // ================= P2: GEMV, permuted tt write =================
    {
        for (int i = tid; i < 2048; i += 256) lme[i] = me[i];
        __syncthreads();
        if (tid < 192) {
            int t = bid * 192 + tid;
            const float* wp = w + t;
            float acc[8];
#pragma unroll
            for (int b = 0; b < 8; b++) acc[b] = 0.f;
#pragma unroll 16
            for (int k = 0; k < 256; k++) {
                float wv = wp[(size_t)k * T_COLS];
                const float4* m4 = reinterpret_cast<const float4*>(&lme[k * 8]);
                float4 m0 = m4[0], m1 = m4[1];
                acc[0] += m0.x * wv; acc[1] += m0.y * wv;
                acc[2] += m0.z * wv; acc[3] += m0.w * wv;
                acc[4] += m1.x * wv; acc[5] += m1.y * wv;
                acc[6] += m1.z * wv; acc[7] += m1.w * wv;
            }
            float bv = bt[t];
#pragma unroll
            for (int b = 0; b < 8; b++) lt[b][tid] = acc[b] + bv;
        }
        __syncthreads();
        if (tid < 192) {
            int u0 = bid * 64;
            int j = tid & 63;
            int c = tid >> 6;               // 0..2, wave-uniform
#pragma unroll
            for (int b = 0; b < 8; b++)
                tt[(size_t)(b * 3 + c) * NU + u0 + j] = lt[b][j * 3 + c];
        }
    }
    gridbar(&bar[0], 768);

    // ================= P3: softmax + tanh*sm + A/s + p-iter + q =================
    if (bid < 24) {
        const int bc = bid;
        const float4* base4 = reinterpret_cast<const float4*>(tt + (size_t)bc * NU);
        const int r0 = tid * 4;
        const int lane = tid & 63, wvi = tid >> 6;   // 4 waves

        float sm[4][16];
        // ---- mix load + max ----
        float lmax[16];
#pragma unroll
        for (int d = 0; d < 16; d++) lmax[d] = -1e30f;
#pragma unroll
        for (int i = 0; i < 4; i++) {
            float4 x0 = base4[(2048 + r0 + i) * 4 + 0];
            float4 x1 = base4[(2048 + r0 + i) * 4 + 1];
            float4 x2 = base4[(2048 + r0 + i) * 4 + 2];
            float4 x3 = base4[(2048 + r0 + i) * 4 + 3];
            sm[i][0] = x0.x; sm[i][1] = x0.y; sm[i][2] = x0.z; sm[i][3] = x0.w;
            sm[i][4] = x1.x; sm[i][5] = x1.y; sm[i][6] = x1.z; sm[i][7] = x1.w;
            sm[i][8] = x2.x; sm[i][9] = x2.y; sm[i][10] = x2.z; sm[i][11] = x2.w;
            sm[i][12] = x3.x; sm[i][13] = x3.y; sm[i][14] = x3.z; sm[i][15] = x3.w;
#pragma unroll
            for (int d = 0; d < 16; d++) lmax[d] = fmaxf(lmax[d], sm[i][d]);
        }
#pragma unroll
        for (int m = 32; m > 0; m >>= 1)
#pragma unroll
            for (int d = 0; d < 16; d++)
                lmax[d] = fmaxf(lmax[d], __shfl_xor(lmax[d], m));
        if (lane == 0) {
#pragma unroll
            for (int d = 0; d < 16; d++) red[wvi * 16 + d] = lmax[d];
        }
        __syncthreads();
        if (tid < 16)
            gmax[tid] = fmaxf(fmaxf(red[tid], red[16 + tid]),
                              fmaxf(red[32 + tid], red[48 + tid]));
        __syncthreads();

        // ---- exp + sum ----
        float lsum[16];
#pragma unroll
        for (int d = 0; d < 16; d++) lsum[d] = 0.f;
#pragma unroll
        for (int i = 0; i < 4; i++)
#pragma unroll
            for (int d = 0; d < 16; d++) {
                sm[i][d] = __expf(sm[i][d] - gmax[d]);
                lsum[d] += sm[i][d];
            }
#pragma unroll
        for (int m = 32; m > 0; m >>= 1)
#pragma unroll
            for (int d = 0; d < 16; d++) lsum[d] += __shfl_xor(lsum[d], m);
        if (lane == 0) {
#pragma unroll
            for (int d = 0; d < 16; d++) red[wvi * 16 + d] = lsum[d];
        }
        __syncthreads();
        if (tid < 16)
            ginv[tid] = 1.f / (red[tid] + red[16 + tid] + red[32 + tid] + red[48 + tid]);
        __syncthreads();
#pragma unroll
        for (int i = 0; i < 4; i++)
#pragma unroll
            for (int d = 0; d < 16; d++) sm[i][d] *= ginv[d];

        // ---- add phase ----
        float asum[4];
#pragma unroll
        for (int i = 0; i < 4; i++) {
            float4 a0 = base4[(1024 + r0 + i) * 4 + 0];
            float4 a1 = base4[(1024 + r0 + i) * 4 + 1];
            float4 a2 = base4[(1024 + r0 + i) * 4 + 2];
            float4 a3 = base4[(1024 + r0 + i) * 4 + 3];
            float av[16];
            av[0] = a0.x; av[1] = a0.y; av[2] = a0.z; av[3] = a0.w;
            av[4] = a1.x; av[5] = a1.y; av[6] = a1.z; av[7] = a1.w;
            av[8] = a2.x; av[9] = a2.y; av[10] = a2.z; av[11] = a2.w;
            av[12] = a3.x; av[13] = a3.y; av[14] = a3.z; av[15] = a3.w;
            float s = 0.f;
#pragma unroll
            for (int d = 0; d < 16; d++) s += tanh_fast(av[d]) * sm[i][d];
            asum[i] = s;
            addsum[(size_t)bc * 1024 + r0 + i] = s;
        }
        sred[tid] = asum[0] + asum[1] + asum[2] + asum[3];

        // ---- mul phase (sm <- tanh(mul)*sm) ----
#pragma unroll
        for (int i = 0; i < 4; i++) {
            float4 m0 = base4[(r0 + i) * 4 + 0];
            float4 m1 = base4[(r0 + i) * 4 + 1];
            float4 m2 = base4[(r0 + i) * 4 + 2];
            float4 m3 = base4[(r0 + i) * 4 + 3];
            float mvv[16];
            mvv[0] = m0.x; mvv[1] = m0.y; mvv[2] = m0.z; mvv[3] = m0.w;
            mvv[4] = m1.x; mvv[5] = m1.y; mvv[6] = m1.z; mvv[7] = m1.w;
            mvv[8] = m2.x; mvv[9] = m2.y; mvv[10] = m2.z; mvv[11] = m2.w;
            mvv[12] = m3.x; mvv[13] = m3.y; mvv[14] = m3.z; mvv[15] = m3.w;
#pragma unroll
            for (int d = 0; d < 16; d++) sm[i][d] = tanh_fast(mvv[d]) * sm[i][d];
            float4* mp = reinterpret_cast<float4*>(&mulp[((size_t)bc * 1024 + r0 + i) * 16]);
            mp[0] = make_float4(sm[i][0], sm[i][1], sm[i][2], sm[i][3]);
            mp[1] = make_float4(sm[i][4], sm[i][5], sm[i][6], sm[i][7]);
            mp[2] = make_float4(sm[i][8], sm[i][9], sm[i][10], sm[i][11]);
            mp[3] = make_float4(sm[i][12], sm[i][13], sm[i][14], sm[i][15]);
        }

        // ---- A / sv reduction ----
#pragma unroll
        for (int d = 0; d < 16; d++)
            red[tid * 16 + d] = sm[0][d] + sm[1][d] + sm[2][d] + sm[3][d];
        __syncthreads();
        {
            int dd = tid >> 4, d = tid & 15;
            int di = dd >> 2, dj = dd & 3;
            float s = 0.f;
#pragma unroll
            for (int a = 0; a < 8; a++) {
                int t0 = di * 64 + a * 8 + dj * 2;
                s += red[t0 * 16 + d] + red[(t0 + 1) * 16 + d];
            }
            Ash[tid] = s * (1.f / 64.f);
        }
        if (tid < 16) {
            int di = tid >> 2, dj = tid & 3;
            float s = 0.f;
#pragma unroll
            for (int a = 0; a < 8; a++) {
                int t0 = di * 64 + a * 8 + dj * 2;
                s += sred[t0] + sred[t0 + 1];
            }
            svl[tid] = s * (1.f / 64.f);
        }
        __syncthreads();

        // ---- p_8 iteration on wave 0 ----
        if (tid < 64) {
            int d2 = tid & 15;
            float arow[16];
#pragma unroll
            for (int d = 0; d < 16; d++) arow[d] = Ash[d2 * 16 + d];
            float sv = svl[d2];
            float pd = 0.f;
            for (int it = 0; it < 8; it++) {
                float x = sv;
#pragma unroll
                for (int d = 0; d < 16; d++) x += arow[d] * __shfl(pd, d, 16);
                pd = x;
            }
            if (tid < 16) pl[tid] = pd;
        }
        __syncthreads();

        // ---- q ----
#pragma unroll
        for (int i = 0; i < 4; i++) {
            float x = asum[i];
#pragma unroll
            for (int d = 0; d < 16; d++) x += sm[i][d] * pl[d];
            q[(size_t)bc * 1024 + r0 + i] = x;
        }
    }
    gridbar(&bar[1], 768);

    // ================= P4: final image (256 active blocks, 2 tasks/thread) =====
    if (bid < 256) {
        int b = bid >> 5, ri = bid & 31;
        for (int i = tid; i < 3072; i += 256) ql3[i] = q[(size_t)b * 3072 + i];
        __syncthreads();

        int h0 = tid >> 6;                // 0..3 (wave-uniform)
        int rj = (tid >> 1) & 31;
        int wh = tid & 1;
        int r = ri * 32 + rj;

        float mr[3][16];
        float as[3];
#pragma unroll
        for (int c = 0; c < 3; c++) {
            const float4* mp4 = reinterpret_cast<const float4*>(
                &mulp[((size_t)(b * 3 + c) * 1024 + r) * 16]);
            float4 v0 = mp4[0], v1 = mp4[1], v2 = mp4[2], v3 = mp4[3];
            mr[c][0] = v0.x; mr[c][1] = v0.y; mr[c][2] = v0.z; mr[c][3] = v0.w;
            mr[c][4] = v1.x; mr[c][5] = v1.y; mr[c][6] = v1.z; mr[c][7] = v1.w;
            mr[c][8] = v2.x; mr[c][9] = v2.y; mr[c][10] = v2.z; mr[c][11] = v2.w;
            mr[c][12] = v3.x; mr[c][13] = v3.y; mr[c][14] = v3.z; mr[c][15] = v3.w;
            as[c] = addsum[(size_t)(b * 3 + c) * 1024 + r];
        }

#pragma unroll
        for (int hh = 0; hh < 2; hh++) {
            int h = h0 + hh * 4;
            float acc[3][4];
#pragma unroll
            for (int c = 0; c < 3; c++)
#pragma unroll
                for (int x = 0; x < 4; x++) acc[c][x] = as[c];
#pragma unroll
            for (int di = 0; di < 4; di++) {
                int qrow = (di * 8 + h) * 32;
#pragma unroll
                for (int dj = 0; dj < 4; dj++) {
#pragma unroll
                    for (int c = 0; c < 3; c++) {
                        float m = mr[c][di * 4 + dj];
                        const float* qb = &ql3[c * 1024 + qrow + dj * 8 + wh * 4];
                        acc[c][0] += m * qb[0];
                        acc[c][1] += m * qb[1];
                        acc[c][2] += m * qb[2];
                        acc[c][3] += m * qb[3];
                    }
                }
            }
            int i = ri * 8 + h;
            int j0 = rj * 8 + wh * 4;
            float4* ob = reinterpret_cast<float4*>(
                &out[((size_t)(b * 256 + i) * 256 + j0) * 3]);
            ob[0] = make_float4(acc[0][0], acc[1][0], acc[2][0], acc[0][1]);
            ob[1] = make_float4(acc[1][1], acc[2][1], acc[0][2], acc[1][2]);
            ob[2] = make_float4(acc[2][2], acc[0][3], acc[1][3], acc[2][3]);
        }
    }
}

// ---------------- fallback path (proven R6 kernels) ----------------
__global__ __launch_bounds__(192) void k2_gemm(const float* __restrict__ w,
                                               const float* __restrict__ bt,
                                               const float* __restrict__ me,
                                               float* __restrict__ tt) {
    __shared__ __align__(16) float lme[2048];
    __shared__ float lt[8][192];
    int tid = threadIdx.x;
    for (int i = tid; i < 2048; i += 192) lme[i] = me[i];
    __syncthreads();
    int t = blockIdx.x * 192 + tid;
    const float* wp = w + t;
    float bv = bt[t];
    float acc[8];
#pragma unroll
    for (int b = 0; b < 8; b++) acc[b] = 0.f;
#pragma unroll 32
    for (int k = 0; k < 256; k++) {
        float wv = wp[(size_t)k * T_COLS];
        const float4* m4 = reinterpret_cast<const float4*>(&lme[k * 8]);
        float4 m0 = m4[0], m1 = m4[1];
        acc[0] += m0.x * wv; acc[1] += m0.y * wv;
        acc[2] += m0.z * wv; acc[3] += m0.w * wv;
        acc[4] += m1.x * wv; acc[5] += m1.y * wv;
        acc[6] += m1.z * wv; acc[7] += m1.w * wv;
    }
#pragma unroll
    for (int b = 0; b < 8; b++) lt[b][tid] = acc[b] + bv;
    __syncthreads();
    int u0 = blockIdx.x * 64;
    int j = tid & 63;
    int c = tid >> 6;
#pragma unroll
    for (int b = 0; b < 8; b++)
        tt[(size_t)(b * 3 + c) * NU + u0 + j] = lt[b][j * 3 + c];
}

#define MVL_STRIDE 1028
__global__ __launch_bounds__(1024) void kC(const float* __restrict__ tt,
                                           float* __restrict__ mulp,
                                           float* __restrict__ addsum,
                                           float* __restrict__ q) {
    int bc = blockIdx.x;
    int r = threadIdx.x;
    int lane = r & 63, wv = r >> 6;
    const float4* base = reinterpret_cast<const float4*>(tt + (size_t)bc * NU);
    __shared__ float redm[16 * 16];
    __shared__ float gm[16], ginv[16];
    __shared__ float mvl[16 * MVL_STRIDE];
    __shared__ float sred[1024];
    __shared__ float Ash[256];
    __shared__ float svl[16], pl[16];
    float mx[16];
    {
        float4 x0 = base[8192 + r * 4 + 0], x1 = base[8192 + r * 4 + 1];
        float4 x2 = base[8192 + r * 4 + 2], x3 = base[8192 + r * 4 + 3];
        mx[0] = x0.x; mx[1] = x0.y; mx[2] = x0.z; mx[3] = x0.w;
        mx[4] = x1.x; mx[5] = x1.y; mx[6] = x1.z; mx[7] = x1.w;
        mx[8] = x2.x; mx[9] = x2.y; mx[10] = x2.z; mx[11] = x2.w;
        mx[12] = x3.x; mx[13] = x3.y; mx[14] = x3.z; mx[15] = x3.w;
    }
    {
        float wred[16];
#pragma unroll
        for (int d = 0; d < 16; d++) wred[d] = mx[d];
#pragma unroll
        for (int m = 32; m > 0; m >>= 1)
#pragma unroll
            for (int d = 0; d < 16; d++)
                wred[d] = fmaxf(wred[d], __shfl_xor(wred[d], m));
        if (lane == 0)
#pragma unroll
            for (int d = 0; d < 16; d++) redm[wv * 16 + d] = wred[d];
    }
    __syncthreads();
    if (r < 16) {
        float m = -1e30f;
#pragma unroll
        for (int w = 0; w < 16; w++) m = fmaxf(m, redm[w * 16 + r]);
        gm[r] = m;
    }
    __syncthreads();
    {
        float wred[16];
#pragma unroll
        for (int d = 0; d < 16; d++) { mx[d] = __expf(mx[d] - gm[d]); wred[d] = mx[d]; }
#pragma unroll
        for (int m = 32; m > 0; m >>= 1)
#pragma unroll
            for (int d = 0; d < 16; d++) wred[d] += __shfl_xor(wred[d], m);
        if (lane == 0)
#pragma unroll
            for (int d = 0; d < 16; d++) redm[wv * 16 + d] = wred[d];
    }
    __syncthreads();
    if (r < 16) {
        float s = 0.f;
#pragma unroll
        for (int w = 0; w < 16; w++) s += redm[w * 16 + r];
        ginv[r] = 1.f / s;
    }
    __syncthreads();
#pragma unroll
    for (int d = 0; d < 16; d++) mx[d] *= ginv[d];
    float asum = 0.f;
    {
        float4 a0 = base[4096 + r * 4 + 0], a1 = base[4096 + r * 4 + 1];
        float4 a2 = base[4096 + r * 4 + 2], a3 = base[4096 + r * 4 + 3];
        float av[16];
        av[0] = a0.x; av[1] = a0.y; av[2] = a0.z; av[3] = a0.w;
        av[4] = a1.x; av[5] = a1.y; av[6] = a1.z; av[7] = a1.w;
        av[8] = a2.x; av[9] = a2.y; av[10] = a2.z; av[11] = a2.w;
        av[12] = a3.x; av[13] = a3.y; av[14] = a3.z; av[15] = a3.w;
#pragma unroll
        for (int d = 0; d < 16; d++) asum += tanh_fast(av[d]) * mx[d];
    }
    addsum[(size_t)bc * 1024 + r] = asum;
    sred[r] = asum;
    float mv[16];
    {
        float4 m0 = base[r * 4 + 0], m1 = base[r * 4 + 1];
        float4 m2 = base[r * 4 + 2], m3 = base[r * 4 + 3];
        mv[0] = m0.x; mv[1] = m0.y; mv[2] = m0.z; mv[3] = m0.w;
        mv[4] = m1.x; mv[5] = m1.y; mv[6] = m1.z; mv[7] = m1.w;
        mv[8] = m2.x; mv[9] = m2.y; mv[10] = m2.z; mv[11] = m2.w;
        mv[12] = m3.x; mv[13] = m3.y; mv[14] = m3.z; mv[15] = m3.w;
#pragma unroll
        for (int d = 0; d < 16; d++) mv[d] = tanh_fast(mv[d]) * mx[d];
    }
    {
        float4* mp = reinterpret_cast<float4*>(&mulp[((size_t)bc * 1024 + r) * 16]);
        mp[0] = make_float4(mv[0], mv[1], mv[2], mv[3]);
        mp[1] = make_float4(mv[4], mv[5], mv[6], mv[7]);
        mp[2] = make_float4(mv[8], mv[9], mv[10], mv[11]);
        mp[3] = make_float4(mv[12], mv[13], mv[14], mv[15]);
    }
#pragma unroll
    for (int d = 0; d < 16; d++) mvl[d * MVL_STRIDE + r] = mv[d];
    __syncthreads();
    if (r < 256) {
        int dd = r >> 4, d = r & 15;
        int di = dd >> 2, dj = dd & 3;
        const float* bse = &mvl[d * MVL_STRIDE + di * 256 + dj * 8];
        float s = 0.f;
        for (int a = 0; a < 8; a++)
#pragma unroll
            for (int e = 0; e < 8; e++) s += bse[a * 32 + e];
        Ash[r] = s * (1.f / 64.f);
    }
    if (r < 16) {
        int di = r >> 2, dj = r & 3;
        float s = 0.f;
        for (int a = 0; a < 8; a++)
#pragma unroll
            for (int e = 0; e < 8; e++) s += sred[di * 256 + a * 32 + dj * 8 + e];
        svl[r] = s * (1.f / 64.f);
    }
    __syncthreads();
    if (r < 64) {
        int d2 = r & 15;
        float arow[16];
#pragma unroll
        for (int d = 0; d < 16; d++) arow[d] = Ash[d2 * 16 + d];
        float sv = svl[d2];
        float pd = 0.f;
        for (int it = 0; it < 8; it++) {
            float x = sv;
#pragma unroll
            for (int d = 0; d < 16; d++) x += arow[d] * __shfl(pd, d, 16);
            pd = x;
        }
        if (r < 16) pl[r] = pd;
    }
    __syncthreads();
    {
        float x = asum;
#pragma unroll
        for (int d = 0; d < 16; d++) x += mv[d] * pl[d];
        q[(size_t)bc * 1024 + r] = x;
    }
}

__global__ __launch_bounds__(512) void k5_final(const float* __restrict__ mulp,
                                                const float* __restrict__ addsum,
                                                const float* __restrict__ q,
                                                float* __restrict__ out) {
    int blk = blockIdx.x;
    int b = blk >> 5, ri = blk & 31;
    int tid = threadIdx.x;
    __shared__ float ql[3072];
    for (int i = tid; i < 3072; i += 512) ql[i] = q[(size_t)b * 3072 + i];
    __syncthreads();
    int h = tid >> 6;
    int rj = (tid >> 1) & 31;
    int wh = tid & 1;
    int r = ri * 32 + rj;
    float mr[3][16];
    float as[3];
#pragma unroll
    for (int c = 0; c < 3; c++) {
        const float4* mp4 = reinterpret_cast<const float4*>(
            &mulp[((size_t)(b * 3 + c) * 1024 + r) * 16]);
        float4 v0 = mp4[0], v1 = mp4[1], v2 = mp4[2], v3 = mp4[3];
        mr[c][0] = v0.x; mr[c][1] = v0.y; mr[c][2] = v0.z; mr[c][3] = v0.w;
        mr[c][4] = v1.x; mr[c][5] = v1.y; mr[c][6] = v1.z; mr[c][7] = v1.w;
        mr[c][8] = v2.x; mr[c][9] = v2.y; mr[c][10] = v2.z; mr[c][11] = v2.w;
        mr[c][12] = v3.x; mr[c][13] = v3.y; mr[c][14] = v3.z; mr[c][15] = v3.w;
        as[c] = addsum[(size_t)(b * 3 + c) * 1024 + r];
    }
    float acc[3][4];
#pragma unroll
    for (int c = 0; c < 3; c++)
#pragma unroll
        for (int w = 0; w < 4; w++) acc[c][w] = as[c];
#pragma unroll
    for (int di = 0; di < 4; di++) {
        int qrow = (di * 8 + h) * 32;
#pragma unroll
        for (int dj = 0; dj < 4; dj++) {
#pragma unroll
            for (int c = 0; c < 3; c++) {
                float m = mr[c][di * 4 + dj];
                const float* qb = &ql[c * 1024 + qrow + dj * 8 + wh * 4];
                acc[c][0] += m * qb[0];
                acc[c][1] += m * qb[1];
                acc[c][2] += m * qb[2];
                acc[c][3] += m * qb[3];
            }
        }
    }
    int i = ri * 8 + h;
    int j0 = rj * 8 + wh * 4;
    float4* ob = reinterpret_cast<float4*>(
        &out[((size_t)(b * 256 + i) * 256 + j0) * 3]);
    ob[0] = make_float4(acc[0][0], acc[1][0], acc[2][0], acc[0][1]);
    ob[1] = make_float4(acc[1][1], acc[2][1], acc[0][2], acc[1][2]);
    ob[2] = make_float4(acc[2][2], acc[0][3], acc[1][3], acc[2][3]);
}

extern "C" void kernel_launch(void* const* d_in, const int* in_sizes, int n_in,
                              void* d_out, int out_size, void* d_ws, size_t ws_size,
                              hipStream_t stream) {
    const float* pe = (const float*)d_in[0];   // (8,8,8,256)
    const float* w  = (const float*)d_in[1];   // (256,147456)
    const float* bt = (const float*)d_in[2];   // (147456,)
    float* ws = (float*)d_ws;

    float* me     = ws + OFF_ME;
    float* tt     = ws + OFF_THETA;
    float* mulp   = ws + OFF_MULP;
    float* addsum = ws + OFF_ADDSUM;
    float* q      = ws + OFF_Q;
    unsigned int* bar = (unsigned int*)(ws + OFF_BAR);
    float* out = (float*)d_out;

    // Residency guard: mega's grid barrier needs all 768 blocks (3/CU) resident.
    int occ = 0;
    (void)hipOccupancyMaxActiveBlocksPerMultiprocessor(&occ, mega, 256, 0);

    k1z<<<8, 1024, 0, stream>>>(pe, me, bar);
    if (occ >= 3) {
        mega<<<768, 256, 0, stream>>>(w, bt, me, tt, mulp, addsum, q, out, bar);
    } else {
        k2_gemm<<<T_COLS / 192, 192, 0, stream>>>(w, bt, me, tt);
        kC<<<24, 1024, 0, stream>>>(tt, mulp, addsum, q);
        k5_final<<<256, 512, 0, stream>>>(mulp, addsum, q, out);
    }
}